// Round 1
// baseline (101.630 us; speedup 1.0000x reference)
//
#include <hip/hip_runtime.h>
#include <hip/hip_bf16.h>

// Problem constants (fixed by the reference)
#define NB     8
#define CIN    14
#define COUT   128
#define HW     384
#define WPR    6          // 384 / 64 words per row
#define OUT_HW 131
#define NTOT   (NB*CIN*HW*HW)   // 16,515,072
#define NWORDS (NTOT/64)        // 258,048

typedef unsigned long long u64;

// ---------------- Kernel 1a: per-block partial sums (deterministic) --------
__global__ __launch_bounds__(256) void reduce_partial(
    const float4* __restrict__ x, double* __restrict__ part, int n4)
{
    double s = 0.0;
    int stride = gridDim.x * blockDim.x;
    for (int idx = blockIdx.x * blockDim.x + threadIdx.x; idx < n4; idx += stride) {
        float4 v = x[idx];
        s += (double)v.x; s += (double)v.y; s += (double)v.z; s += (double)v.w;
    }
    // wave reduce (64 lanes)
    for (int off = 32; off; off >>= 1) s += __shfl_down(s, off);
    __shared__ double wsum[4];
    int lane = threadIdx.x & 63, wv = threadIdx.x >> 6;
    if (lane == 0) wsum[wv] = s;
    __syncthreads();
    if (threadIdx.x == 0) part[blockIdx.x] = ((wsum[0] + wsum[1]) + (wsum[2] + wsum[3]));
}

// ---------------- Kernel 1b: final mean ------------------------------------
__global__ __launch_bounds__(256) void reduce_final(
    const double* __restrict__ part, float* __restrict__ meanp, int nb)
{
    double s = 0.0;
    for (int i = threadIdx.x; i < nb; i += 256) s += part[i];
    for (int off = 32; off; off >>= 1) s += __shfl_down(s, off);
    __shared__ double wsum[4];
    int lane = threadIdx.x & 63, wv = threadIdx.x >> 6;
    if (lane == 0) wsum[wv] = s;
    __syncthreads();
    if (threadIdx.x == 0)
        *meanp = (float)((((wsum[0] + wsum[1]) + (wsum[2] + wsum[3])) / (double)NTOT));
}

// ---------------- Kernel 2: binarize + bit-pack via ballot -----------------
__global__ __launch_bounds__(256) void pack_bits(
    const float* __restrict__ x, const float* __restrict__ meanp,
    u64* __restrict__ xb)
{
    float m = *meanp;
    int gtid = blockIdx.x * blockDim.x + threadIdx.x;
    int wid  = gtid >> 6;
    int lane = threadIdx.x & 63;
    int nw   = (gridDim.x * blockDim.x) >> 6;
    for (int w = wid; w < NWORDS; w += nw) {
        float v = x[(size_t)w * 64 + lane];
        u64 mask = __ballot(v >= m);     // bit l = lane l = column offset l
        if (lane == 0) xb[w] = mask;
    }
}

// ---------------- Kernel 3: fused conv1+conv2+conv3 ------------------------
// One block per (n, output row i). 256 threads.
__global__ __launch_bounds__(256) void conv_fused(
    const float* __restrict__ w1, const float* __restrict__ b1,
    const float* __restrict__ w2, const float* __restrict__ b2,
    const float* __restrict__ w3, const float* __restrict__ b3,
    const u64* __restrict__ xbin, float* __restrict__ out)
{
    __shared__ u64 xrows[CIN][7][WPR];        // 7 input rows of all 14 channels
    __shared__ u64 y2lo[OUT_HW], y2hi[OUT_HW];
    __shared__ u64 w3lo[COUT], w3hi[COUT];
    __shared__ unsigned int w2b[COUT];
    __shared__ int b2i[COUT], b3i[COUT];
    __shared__ unsigned int w1row[CIN][7];
    __shared__ int b1i[CIN];
    __shared__ u64 borderLo, borderHi;

    const int tid = threadIdx.x;
    const int blk = blockIdx.x;
    const int n = blk / OUT_HW;
    const int i = blk - n * OUT_HW;

    // ---- phase 0: pack weights into LDS ----
    if (tid < COUT) {
        u64 lo = 0, hi = 0;
        const float* wr = w3 + tid * COUT;
        #pragma unroll 8
        for (int c = 0; c < 64; c++) lo |= (u64)(wr[c] >= 0.f) << c;
        #pragma unroll 8
        for (int c = 0; c < 64; c++) hi |= (u64)(wr[64 + c] >= 0.f) << c;
        w3lo[tid] = lo; w3hi[tid] = hi;
        unsigned int wb = 0;
        const float* w2r = w2 + tid * CIN;
        for (int c = 0; c < CIN; c++) wb |= (unsigned int)(w2r[c] >= 0.f) << c;
        w2b[tid] = wb;
        b2i[tid] = (int)rintf(b2[tid]);
        b3i[tid] = (int)rintf(b3[tid]);
    } else {
        int t = tid - COUT;
        if (t < CIN * 7) {
            int ci = t / 7, dy = t - ci * 7;
            unsigned int r = 0;
            const float* w1r = w1 + (ci * 7 + dy) * 7;
            for (int dx = 0; dx < 7; dx++) r |= (unsigned int)(w1r[dx] >= 0.f) << dx;
            w1row[ci][dy] = r;
        } else if (t < CIN * 7 + CIN) {
            int ci = t - CIN * 7;
            b1i[ci] = (int)rintf(b1[ci]);
        }
    }

    // ---- phase 0.5: stage the 7 needed xbin rows (p-3..p+3), all channels ----
    const int p = 3 * i - 4;   // conv1 output row needed by this block (i>=2 interior)
    for (int t = tid; t < CIN * 7 * WPR; t += 256) {
        int ci = t / (7 * WPR);
        int rem = t - ci * (7 * WPR);
        int dy = rem / WPR;
        int k  = rem - dy * WPR;
        int r  = p + dy - 3;
        u64 v = 0;
        if (r >= 0 && r < HW) v = xbin[((n * CIN + ci) * HW + r) * WPR + k];
        xrows[ci][dy][k] = v;
    }
    __syncthreads();

    if (tid == 0) {   // conv2 pad frame: bits = sign(round(b2))
        u64 lo = 0, hi = 0;
        for (int c = 0; c < 64; c++) lo |= (u64)(b2i[c] >= 0) << c;
        for (int c = 0; c < 64; c++) hi |= (u64)(b2i[64 + c] >= 0) << c;
        borderLo = lo; borderHi = hi;
    }
    __syncthreads();

    // ---- phase 1: per-pixel y2 vector (128 bits) for j = tid ----
    if (i >= 1 && tid >= 1 && tid < OUT_HW) {
        const int j = tid;
        const int h = 3 * i - 1, w = 3 * j - 1;   // conv2 output coords (0..389)
        u64 lo, hi;
        if (h >= 3 && h < 387 && w >= 3 && w < 387) {
            const int q  = w - 3;     // conv1 output col
            const int c0 = q - 3;     // leftmost input col of 7-tap window
            unsigned int vm = 0x7Fu;
            if (c0 < 0)   vm &= 0x7Fu << (-c0);
            if (c0 > 377) vm &= (1u << (384 - c0)) - 1u;
            const int vpop = __popc(vm);
            unsigned int y1v = 0;
            for (int ci = 0; ci < CIN; ci++) {
                int s = b1i[ci];
                #pragma unroll
                for (int dy = 0; dy < 7; dy++) {
                    int r = p + dy - 3;
                    if (r < 0 || r >= HW) continue;
                    unsigned int bits;
                    if (c0 >= 0) {
                        int k = c0 >> 6, off = c0 & 63;
                        u64 v = xrows[ci][dy][k] >> off;
                        if (off > 57 && k < WPR - 1) v |= xrows[ci][dy][k + 1] << (64 - off);
                        bits = (unsigned int)v & 0x7Fu;
                    } else {
                        bits = ((unsigned int)(xrows[ci][dy][0] << (-c0))) & 0x7Fu;
                    }
                    unsigned int xo = (bits ^ w1row[ci][dy]) & vm;
                    s += vpop - 2 * __popc(xo);
                }
                y1v |= (unsigned int)(s >= 0) << ci;
            }
            lo = 0; hi = 0;
            #pragma unroll 4
            for (int co = 0; co < 64; co++) {
                int s = CIN - 2 * __popc((y1v ^ w2b[co]) & 0x3FFFu) + b2i[co];
                lo |= (u64)(s >= 0) << co;
            }
            #pragma unroll 4
            for (int co = 0; co < 64; co++) {
                int s = CIN - 2 * __popc((y1v ^ w2b[64 + co]) & 0x3FFFu) + b2i[64 + co];
                hi |= (u64)(s >= 0) << co;
            }
        } else {
            lo = borderLo; hi = borderHi;   // conv2 pad frame
        }
        y2lo[j] = lo; y2hi[j] = hi;
    }
    __syncthreads();

    // ---- phase 2: conv3 (1x1, 128->128) + sign, write outputs ----
    const bool rowZero = (i == 0);
    for (int u = tid; u < COUT * OUT_HW; u += 256) {
        int co = u / OUT_HW;
        int j  = u - co * OUT_HW;
        int s;
        if (rowZero || j == 0) {
            s = b3i[co];            // conv3 zero-pad sample
        } else {
            s = COUT + b3i[co]
              - 2 * (__popcll(y2lo[j] ^ w3lo[co]) + __popcll(y2hi[j] ^ w3hi[co]));
        }
        out[(((size_t)n * COUT + co) * OUT_HW + i) * OUT_HW + j] = (s >= 0) ? 1.0f : -1.0f;
    }
}

extern "C" void kernel_launch(void* const* d_in, const int* in_sizes, int n_in,
                              void* d_out, int out_size, void* d_ws, size_t ws_size,
                              hipStream_t stream) {
    const float* x  = (const float*)d_in[0];
    const float* w1 = (const float*)d_in[1];
    const float* b1 = (const float*)d_in[2];
    const float* w2 = (const float*)d_in[3];
    const float* b2 = (const float*)d_in[4];
    const float* w3 = (const float*)d_in[5];
    const float* b3 = (const float*)d_in[6];
    float* out = (float*)d_out;

    // workspace layout
    double* partials = (double*)d_ws;                          // 1024 * 8B
    float*  meanp    = (float*)((char*)d_ws + 8192);
    u64*    xbin     = (u64*)((char*)d_ws + 16384);            // 258,048 * 8B

    reduce_partial<<<1024, 256, 0, stream>>>((const float4*)x, partials, NTOT / 4);
    reduce_final<<<1, 256, 0, stream>>>(partials, meanp, 1024);
    pack_bits<<<1024, 256, 0, stream>>>(x, meanp, xbin);
    conv_fused<<<NB * OUT_HW, 256, 0, stream>>>(w1, b1, w2, b2, w3, b3, xbin, out);
}

// Round 2
// 92.219 us; speedup vs baseline: 1.1020x; 1.1020x over previous
//
#include <hip/hip_runtime.h>
#include <hip/hip_bf16.h>

// Problem constants (fixed by the reference)
#define NB     8
#define CIN    14
#define COUT   128
#define HW     384
#define WPR    6          // 384 / 64 words per row
#define OUT_HW 131
#define NTOT   (NB*CIN*HW*HW)   // 16,515,072
#define NWORDS (NTOT/64)        // 258,048

typedef unsigned long long u64;
typedef unsigned int u32;

struct PackedW {
    u64 w3lo[COUT], w3hi[COUT];   // sign bits of w3 row co: cols 0..63 / 64..127
    u64 borderLo, borderHi;       // conv2 pad-frame y2 bits = sign(round(b2))
    u32 w2b[COUT];
    int b2i[COUT], b3i[COUT];
    u32 w1row[98];                // [ci*7+dy]
    int b1i[CIN];
    u32 b3bits[4];                // sign(round(b3)) as 4x32-bit planes over co
};

// ---------------- Kernel 1: per-block partial sums (deterministic) ---------
__global__ __launch_bounds__(256) void reduce_partial(
    const float4* __restrict__ x, double* __restrict__ part, int n4)
{
    double s = 0.0;
    int stride = gridDim.x * blockDim.x;
    for (int idx = blockIdx.x * blockDim.x + threadIdx.x; idx < n4; idx += stride) {
        float4 v = x[idx];
        s += (double)v.x; s += (double)v.y; s += (double)v.z; s += (double)v.w;
    }
    for (int off = 32; off; off >>= 1) s += __shfl_down(s, off);
    __shared__ double wsum[4];
    int lane = threadIdx.x & 63, wv = threadIdx.x >> 6;
    if (lane == 0) wsum[wv] = s;
    __syncthreads();
    if (threadIdx.x == 0) part[blockIdx.x] = ((wsum[0] + wsum[1]) + (wsum[2] + wsum[3]));
}

// ---------------- Kernel 2: final mean + one-time weight packing -----------
__global__ __launch_bounds__(256) void finalize_pack(
    const double* __restrict__ part, float* __restrict__ meanp,
    const float* __restrict__ w1, const float* __restrict__ b1,
    const float* __restrict__ w2, const float* __restrict__ b2,
    const float* __restrict__ w3, const float* __restrict__ b3,
    PackedW* __restrict__ pw)
{
    const int tid = threadIdx.x;
    const int lane = tid & 63, wv = tid >> 6;

    // ---- deterministic mean ----
    double s = 0.0;
    for (int i = tid; i < 1024; i += 256) s += part[i];
    for (int off = 32; off; off >>= 1) s += __shfl_down(s, off);
    __shared__ double wsum[4];
    if (lane == 0) wsum[wv] = s;
    __syncthreads();
    if (tid == 0)
        *meanp = (float)((((wsum[0] + wsum[1]) + (wsum[2] + wsum[3])) / (double)NTOT));

    // ---- pack weights (one-time) ----
    if (tid < COUT) {
        const float* wr = w3 + tid * COUT;
        u64 lo = 0;
        #pragma unroll 8
        for (int c = 0; c < 64; c++) lo |= (u64)(wr[c] >= 0.f) << c;
        pw->w3lo[tid] = lo;
        u32 wb = 0;
        const float* w2r = w2 + tid * CIN;
        for (int c = 0; c < CIN; c++) wb |= (u32)(w2r[c] >= 0.f) << c;
        pw->w2b[tid] = wb;
        int bi2 = (int)rintf(b2[tid]); pw->b2i[tid] = bi2;
        int bi3 = (int)rintf(b3[tid]); pw->b3i[tid] = bi3;
        u64 ball2 = __ballot(bi2 >= 0);
        u64 ball3 = __ballot(bi3 >= 0);
        if (lane == 0) {
            if (wv == 0) pw->borderLo = ball2; else pw->borderHi = ball2;
            pw->b3bits[wv * 2]     = (u32)ball3;
            pw->b3bits[wv * 2 + 1] = (u32)(ball3 >> 32);
        }
    } else {
        int t = tid - COUT;   // 0..127
        const float* wr = w3 + t * COUT + 64;
        u64 hi = 0;
        #pragma unroll 8
        for (int c = 0; c < 64; c++) hi |= (u64)(wr[c] >= 0.f) << c;
        pw->w3hi[t] = hi;
        if (t < 98) {
            int ci = t / 7, dy = t - ci * 7;
            u32 r = 0;
            const float* w1r = w1 + (ci * 7 + dy) * 7;
            for (int dx = 0; dx < 7; dx++) r |= (u32)(w1r[dx] >= 0.f) << dx;
            pw->w1row[t] = r;
        } else if (t < 112) {
            pw->b1i[t - 98] = (int)rintf(b1[t - 98]);
        }
    }
}

// ---------------- Kernel 3: binarize + bit-pack via ballot -----------------
__global__ __launch_bounds__(256) void pack_bits(
    const float* __restrict__ x, const float* __restrict__ meanp,
    u64* __restrict__ xb)
{
    float m = *meanp;
    int gtid = blockIdx.x * blockDim.x + threadIdx.x;
    int wid  = gtid >> 6;
    int lane = threadIdx.x & 63;
    int nw   = (gridDim.x * blockDim.x) >> 6;
    for (int w = wid; w < NWORDS; w += nw) {
        float v = x[(size_t)w * 64 + lane];
        u64 mask = __ballot(v >= m);
        if (lane == 0) xb[w] = mask;
    }
}

// ---------------- Kernel 4: fused conv1+conv2+conv3 + unpack ---------------
// One block per (n, output row i). 256 threads.
__global__ __launch_bounds__(256) void bnn_fused(
    const u64* __restrict__ xbin, const PackedW* __restrict__ pw,
    float* __restrict__ out)
{
    __shared__ u64 xrows[CIN][7][WPR];
    __shared__ u64 y2lo[OUT_HW], y2hi[OUT_HW];
    __shared__ u32 zw[4][132];          // conv3 result bits: [co-plane][j]
    __shared__ u32 w1row_s[98];
    __shared__ int b1i_s[CIN];
    __shared__ u32 w2b_s[COUT];
    __shared__ int b2i_s[COUT];
    __shared__ u64 border_s[2];

    const int tid  = threadIdx.x;
    const int lane = tid & 63;
    const int wv   = tid >> 6;
    const int blk  = blockIdx.x;
    const int n = blk / OUT_HW;
    const int i = blk - n * OUT_HW;

    // ---- stage small weights into LDS ----
    if (tid < 98) w1row_s[tid] = pw->w1row[tid];
    else if (tid < 112) b1i_s[tid - 98] = pw->b1i[tid - 98];
    else if (tid < 114) border_s[tid - 112] = (&pw->borderLo)[tid - 112];
    if (tid >= COUT) {
        w2b_s[tid - COUT] = pw->w2b[tid - COUT];
        b2i_s[tid - COUT] = pw->b2i[tid - COUT];
    }

    // ---- init zw (conv3 zero-pad samples: j==0, and all j when i==0) ----
    if (i == 0) {
        for (int idx = tid; idx < 4 * OUT_HW; idx += 256) {
            int p = idx & 3, j = idx >> 2;
            zw[p][j] = pw->b3bits[p];
        }
    } else if (tid < 4) {
        zw[tid][0] = pw->b3bits[tid];
    }

    // ---- stage the 7 needed xbin rows, all channels ----
    const int p0 = 3 * i - 4;   // conv1 output row needed by this block
    if (i >= 1) {
        for (int t = tid; t < CIN * 7 * WPR; t += 256) {
            int ci = t / (7 * WPR);
            int rem = t - ci * (7 * WPR);
            int dy = rem / WPR;
            int k  = rem - dy * WPR;
            int r  = p0 + dy - 3;
            u64 v = 0;
            if (r >= 0 && r < HW) v = xbin[((n * CIN + ci) * HW + r) * WPR + k];
            xrows[ci][dy][k] = v;
        }
    }
    __syncthreads();

    // ---- phase A: per-pixel y2 vector (128 bits) for j = tid ----
    if (i >= 1 && tid >= 1 && tid < OUT_HW) {
        const int j = tid;
        const int h = 3 * i - 1, w = 3 * j - 1;   // conv2 output coords
        u64 lo, hi;
        if (h >= 3 && h < 387 && w >= 3 && w < 387) {
            const int q  = w - 3;     // conv1 output col
            const int c0 = q - 3;     // leftmost input col of 7-tap window
            u32 vm = 0x7Fu;
            if (c0 < 0)   vm &= 0x7Fu << (-c0);
            if (c0 > 377) vm &= (1u << (384 - c0)) - 1u;
            const int vpop = __popc(vm);
            u32 y1v = 0;
            for (int ci = 0; ci < CIN; ci++) {
                int s = b1i_s[ci];
                #pragma unroll
                for (int dy = 0; dy < 7; dy++) {
                    int r = p0 + dy - 3;
                    if (r < 0 || r >= HW) continue;
                    u32 bits;
                    if (c0 >= 0) {
                        int k = c0 >> 6, off = c0 & 63;
                        u64 v = xrows[ci][dy][k] >> off;
                        if (off > 57 && k < WPR - 1) v |= xrows[ci][dy][k + 1] << (64 - off);
                        bits = (u32)v & 0x7Fu;
                    } else {
                        bits = ((u32)(xrows[ci][dy][0] << (-c0))) & 0x7Fu;
                    }
                    u32 xo = (bits ^ w1row_s[ci * 7 + dy]) & vm;
                    s += vpop - 2 * __popc(xo);
                }
                y1v |= (u32)(s >= 0) << ci;
            }
            lo = 0; hi = 0;
            #pragma unroll 4
            for (int co = 0; co < 64; co++) {
                int s = CIN - 2 * __popc((y1v ^ w2b_s[co]) & 0x3FFFu) + b2i_s[co];
                lo |= (u64)(s >= 0) << co;
            }
            #pragma unroll 4
            for (int co = 0; co < 64; co++) {
                int s = CIN - 2 * __popc((y1v ^ w2b_s[64 + co]) & 0x3FFFu) + b2i_s[64 + co];
                hi |= (u64)(s >= 0) << co;
            }
        } else {
            lo = border_s[0]; hi = border_s[1];   // conv2 pad frame
        }
        y2lo[j] = lo; y2hi[j] = hi;
    }

    // ---- per-lane w3 rows (registers), loads overlap phase A ----
    u64 w3lo_a = pw->w3lo[lane],      w3hi_a = pw->w3hi[lane];
    u64 w3lo_b = pw->w3lo[64 + lane], w3hi_b = pw->w3hi[64 + lane];
    int b3_a   = pw->b3i[lane],       b3_b   = pw->b3i[64 + lane];
    __syncthreads();

    // ---- phase B: conv3 via ballot (lanes = co) ----
    if (i >= 1) {
        const int half = wv & 1;
        const u64 wlo = half ? w3lo_b : w3lo_a;
        const u64 whi = half ? w3hi_b : w3hi_a;
        const int bb  = COUT + (half ? b3_b : b3_a);
        for (int t = wv; t < 260; t += 4) {
            const int j = 1 + (t >> 1);
            u64 ylo = y2lo[j], yhi = y2hi[j];   // LDS broadcast
            int s = bb - 2 * (int)(__popcll(ylo ^ wlo) + __popcll(yhi ^ whi));
            u64 ball = __ballot(s >= 0);
            if (lane == 0) {
                zw[half * 2][j]     = (u32)ball;
                zw[half * 2 + 1][j] = (u32)(ball >> 32);
            }
        }
    }
    __syncthreads();

    // ---- phase C: unpack bits -> +-1 floats, coalesced stores (lanes = j) ----
    const size_t base_ni = (size_t)n * COUT * (OUT_HW * OUT_HW) + (size_t)i * OUT_HW;
    for (int co = wv; co < COUT; co += 4) {
        const u32* zp = zw[co >> 5];
        const int bsel = co & 31;
        float* orow = out + base_ni + (size_t)co * (OUT_HW * OUT_HW);
        #pragma unroll
        for (int k = 0; k < 3; k++) {
            int j = k * 64 + lane;
            if (j < OUT_HW) orow[j] = ((zp[j] >> bsel) & 1) ? 1.0f : -1.0f;
        }
    }
}

extern "C" void kernel_launch(void* const* d_in, const int* in_sizes, int n_in,
                              void* d_out, int out_size, void* d_ws, size_t ws_size,
                              hipStream_t stream) {
    const float* x  = (const float*)d_in[0];
    const float* w1 = (const float*)d_in[1];
    const float* b1 = (const float*)d_in[2];
    const float* w2 = (const float*)d_in[3];
    const float* b2 = (const float*)d_in[4];
    const float* w3 = (const float*)d_in[5];
    const float* b3 = (const float*)d_in[6];
    float* out = (float*)d_out;

    // workspace layout
    double*  partials = (double*)d_ws;                         // 1024 * 8B
    float*   meanp    = (float*)((char*)d_ws + 8192);
    u64*     xbin     = (u64*)((char*)d_ws + 16384);           // 258,048 * 8B
    PackedW* pw       = (PackedW*)((char*)d_ws + 16384 + NWORDS * 8);

    reduce_partial<<<1024, 256, 0, stream>>>((const float4*)x, partials, NTOT / 4);
    finalize_pack<<<1, 256, 0, stream>>>(partials, meanp, w1, b1, w2, b2, w3, b3, pw);
    pack_bits<<<1024, 256, 0, stream>>>(x, meanp, xbin);
    bnn_fused<<<NB * OUT_HW, 256, 0, stream>>>(xbin, pw, out);
}